// Round 13
// baseline (4273.809 us; speedup 1.0000x reference)
//
#include <hip/hip_runtime.h>
#include <hip/hip_bf16.h>

// LSTM trajectory predictor, Round 13: encoder pairs move to a 256x128 block
// tile (4 waves of 128x64, A-streamed) -> 24 LDS reads per 96 MFMAs instead
// of 16 per 48 (-33% LDS traffic per FLOP, half the barriers). 128 blocks
// per cell, paired -> 256 blocks = 1 block/CU. Decoder + solo L0(0) keep the
// proven 128x128 kernel (R5/R12) verbatim.

#define HDIM 512
#define BDIM 2048
#define T_HIST 50
#define T_FUT 30

typedef __attribute__((ext_vector_type(8))) short short8;
typedef __attribute__((ext_vector_type(4))) float f32x4;

#define AS1(p) ((const __attribute__((address_space(1))) void*)(p))
#define AS3(p) ((__attribute__((address_space(3))) void*)(p))

__device__ __forceinline__ ushort f2bf(float f) {
    union { float f; unsigned u; } v; v.f = f;
    unsigned r = v.u + 0x7fff + ((v.u >> 16) & 1);   // RNE
    return (ushort)(r >> 16);
}
__device__ __forceinline__ float bf2f(ushort h) {
    union { unsigned u; float f; } v; v.u = ((unsigned)h) << 16;
    return v.f;
}

// Region layout (R rows x 32 k, 16B slots, 4 slots/row):
// q = row>>1, t = ((row&1)<<2)|slot, phys = q*8 + (t ^ (q&7)).  Bijective;
// frag reads (16 rows x 4 slots) spread 2-way max across banks (free).
__device__ __forceinline__ int swz(int row, int slot) {
    int q = row >> 1;
    int t = ((row & 1) << 2) | slot;
    return q * 8 + (t ^ (q & 7));
}

// ---- weight prep: fp32 [2048][512] -> bf16 hi/lo, rows permuted so a
// block's 128 n-rows = 32 units x 4 gates (gate index in bits [4:5] of rp).
// input row = g*512 + u ; rp = (u>>5)*128 + ((u>>4)&1)*64 + g*16 + (u&15)
struct SplitSrc { const float* src[6]; };

__global__ __launch_bounds__(256) void split_weights(SplitSrc s, ushort* __restrict__ hi,
                                                     ushort* __restrict__ lo) {
    int row = blockIdx.x;             // g*512 + u
    int j = blockIdx.y;               // matrix index
    int g = row >> 9, u = row & 511;
    int rp = (u >> 5) * 128 + ((u >> 4) & 1) * 64 + g * 16 + (u & 15);
    const float* S = s.src[j] + (size_t)row * HDIM;
    ushort* H = hi + ((size_t)j * 2048 + rp) * HDIM;
    ushort* L = lo + ((size_t)j * 2048 + rp) * HDIM;
    for (int k = threadIdx.x; k < HDIM; k += 256) {
        float w = S[k];
        ushort hb = f2bf(w);
        H[k] = hb;
        L[k] = f2bf(w - bf2f(hb));
    }
}

// ---- cell descriptor (one LSTM cell = one 2048x2048xK GEMM + gates) ----
struct CellDesc {
    const ushort *A1h, *A1l, *W1h, *W1l;
    const ushort *A2h, *A2l, *W2h, *W2l;
    const float *x; const float *Wx;
    const float *bih, *bhh;
    float* c; ushort *hh; ushort *hl;
    int np, xs, Kx;
};

// ================= 128x128 cell kernel (decoder + solo) — R12 verbatim ======
__global__ __launch_bounds__(256, 2) void lstm_cells(CellDesc dA, CellDesc dB) {
    __shared__ __align__(16) ushort lds[2 * 16384];

    const CellDesc d = (blockIdx.x >> 8) ? dB : dA;

    const int tid = threadIdx.x;
    const int w = tid >> 6, l = tid & 63;
    const int wm = w >> 1, wn = w & 1;
    const int lrow = l & 15, lk = l >> 4;

    int id = blockIdx.x & 255;
    int xcd = id & 7, rr = id >> 3;
    int bx = (xcd & 3) * 4 + (rr & 3);
    int by = (xcd >> 2) * 8 + (rr >> 2);
    const int m0 = by * 128;
    const int n0 = bx * 128;
    const int u  = bx * 32 + wn * 16 + lrow;

    f32x4 acc[4][4];

    #pragma unroll
    for (int g = 0; g < 4; ++g) {
        float b = d.bih[g * HDIM + u] + d.bhh[g * HDIM + u];
        f32x4 bv = {b, b, b, b};
        #pragma unroll
        for (int fm = 0; fm < 4; ++fm) acc[fm][g] = bv;
    }
    if (d.Kx > 0) {
        for (int kx = 0; kx < d.Kx; ++kx) {
            float wv[4];
            #pragma unroll
            for (int g = 0; g < 4; ++g) wv[g] = d.Wx[(size_t)(g * HDIM + u) * d.Kx + kx];
            #pragma unroll
            for (int fm = 0; fm < 4; ++fm)
                #pragma unroll
                for (int r = 0; r < 4; ++r) {
                    int m = m0 + wm * 64 + fm * 16 + lk * 4 + r;
                    float xv = d.x[(size_t)m * d.xs + kx];
                    #pragma unroll
                    for (int g = 0; g < 4; ++g) acc[fm][g][r] += xv * wv[g];
                }
        }
    }

    auto STAGE = [&](int t) {
        int buf = t & 1;
        int p = t >> 4;
        int kc = (t & 15) * 32;
        const ushort* Ah = p ? d.A2h : d.A1h;
        const ushort* Al = p ? d.A2l : d.A1l;
        const ushort* Bh = p ? d.W2h : d.W1h;
        const ushort* Bl = p ? d.W2l : d.W1l;
        ushort* base = &lds[buf * 16384];
        #pragma unroll
        for (int it = 0; it < 2; ++it) {
            int db = (w * 2 + it) * 64;
            int dd = db + l;
            int q = dd >> 3, tp = dd & 7;
            int tl = tp ^ (q & 7);
            int r = (q << 1) | (tl >> 2);
            int s = tl & 3;
            size_t go = (size_t)r * HDIM + kc + s * 8;
            __builtin_amdgcn_global_load_lds(AS1(Ah + (size_t)m0 * HDIM + go),
                                             AS3(base + db * 8), 16, 0, 0);
            __builtin_amdgcn_global_load_lds(AS1(Al + (size_t)m0 * HDIM + go),
                                             AS3(base + 4096 + db * 8), 16, 0, 0);
            __builtin_amdgcn_global_load_lds(AS1(Bh + (size_t)n0 * HDIM + go),
                                             AS3(base + 8192 + db * 8), 16, 0, 0);
            __builtin_amdgcn_global_load_lds(AS1(Bl + (size_t)n0 * HDIM + go),
                                             AS3(base + 12288 + db * 8), 16, 0, 0);
        }
    };

    const int nch = d.np * 16;
    STAGE(0);

    for (int t = 0; t < nch; ++t) {
        __syncthreads();
        if (t + 1 < nch) STAGE(t + 1);
        ushort* base = &lds[(t & 1) * 16384];
        short8 ah[4], al[4], bh[4], bl[4];
        #pragma unroll
        for (int fm = 0; fm < 4; ++fm) {
            int row = wm * 64 + fm * 16 + lrow;
            int off = swz(row, lk) * 8;
            ah[fm] = *(const short8*)(base + off);
            al[fm] = *(const short8*)(base + 4096 + off);
        }
        #pragma unroll
        for (int g = 0; g < 4; ++g) {
            int row = wn * 64 + g * 16 + lrow;
            int off = swz(row, lk) * 8;
            bh[g] = *(const short8*)(base + 8192 + off);
            bl[g] = *(const short8*)(base + 12288 + off);
        }
        #pragma unroll
        for (int fm = 0; fm < 4; ++fm)
            #pragma unroll
            for (int g = 0; g < 4; ++g)
                acc[fm][g] = __builtin_amdgcn_mfma_f32_16x16x32_bf16(
                    ah[fm], bh[g], acc[fm][g], 0, 0, 0);
        #pragma unroll
        for (int fm = 0; fm < 4; ++fm)
            #pragma unroll
            for (int g = 0; g < 4; ++g)
                acc[fm][g] = __builtin_amdgcn_mfma_f32_16x16x32_bf16(
                    al[fm], bh[g], acc[fm][g], 0, 0, 0);
        #pragma unroll
        for (int fm = 0; fm < 4; ++fm)
            #pragma unroll
            for (int g = 0; g < 4; ++g)
                acc[fm][g] = __builtin_amdgcn_mfma_f32_16x16x32_bf16(
                    ah[fm], bl[g], acc[fm][g], 0, 0, 0);
    }

    #pragma unroll
    for (int fm = 0; fm < 4; ++fm)
        #pragma unroll
        for (int r = 0; r < 4; ++r) {
            int m = m0 + wm * 64 + fm * 16 + lk * 4 + r;
            size_t idx = (size_t)m * HDIM + u;
            float zi = acc[fm][0][r], zf = acc[fm][1][r];
            float zg = acc[fm][2][r], zo = acc[fm][3][r];
            float ig = 1.f / (1.f + __expf(-zi));
            float fg = 1.f / (1.f + __expf(-zf));
            float gg = 2.f / (1.f + __expf(-2.f * zg)) - 1.f;
            float og = 1.f / (1.f + __expf(-zo));
            float cn = fg * d.c[idx] + ig * gg;
            float hn = og * (2.f / (1.f + __expf(-2.f * cn)) - 1.f);
            d.c[idx] = cn;
            ushort hb = f2bf(hn);
            d.hh[idx] = hb;
            d.hl[idx] = f2bf(hn - bf2f(hb));
        }
}

// ================= 256x128 cell kernel (encoder pairs) ======================
// 4 waves 2m x 2n, wave tile 128x64: per chunk 24 LDS reads feed 96 MFMAs.
// LDS: 2 buffers x 48KB (A_hi 16K @0, A_lo @8192, B_hi 8K @16384, B_lo @20480
// in ushort offsets). 128 blocks per cell; blocks [0,128) dA, [128,256) dB.
__global__ __launch_bounds__(256, 1) void lstm_cells_big(CellDesc dA, CellDesc dB) {
    __shared__ __align__(16) ushort lds[2 * 24576];   // 96 KB

    const CellDesc d = (blockIdx.x >> 7) ? dB : dA;

    const int tid = threadIdx.x;
    const int w = tid >> 6, l = tid & 63;
    const int wm = w >> 1, wn = w & 1;
    const int lrow = l & 15, lk = l >> 4;

    // XCD-chunked swizzle for 128 blocks: 4bx x 4by per XCD
    int id = blockIdx.x & 127;
    int xcd = id & 7, rr = id >> 3;                 // rr 0..15
    int bx = (xcd & 3) * 4 + (rr & 3);              // 0..15
    int by = (xcd >> 2) * 4 + (rr >> 2);            // 0..7
    const int m0 = by * 256;
    const int n0 = bx * 128;
    const int u  = bx * 32 + wn * 16 + lrow;

    f32x4 acc[8][4];   // [m-frag][gate]

    #pragma unroll
    for (int g = 0; g < 4; ++g) {
        float b = d.bih[g * HDIM + u] + d.bhh[g * HDIM + u];
        f32x4 bv = {b, b, b, b};
        #pragma unroll
        for (int fm = 0; fm < 8; ++fm) acc[fm][g] = bv;
    }
    if (d.Kx > 0) {
        for (int kx = 0; kx < d.Kx; ++kx) {
            float wv[4];
            #pragma unroll
            for (int g = 0; g < 4; ++g) wv[g] = d.Wx[(size_t)(g * HDIM + u) * d.Kx + kx];
            #pragma unroll
            for (int fm = 0; fm < 8; ++fm)
                #pragma unroll
                for (int r = 0; r < 4; ++r) {
                    int m = m0 + wm * 128 + fm * 16 + lk * 4 + r;
                    float xv = d.x[(size_t)m * d.xs + kx];
                    #pragma unroll
                    for (int g = 0; g < 4; ++g) acc[fm][g][r] += xv * wv[g];
                }
        }
    }

    // staging: A 2x1024 slots (4 iters/region), B 2x512 slots (2 iters)
    auto STAGE = [&](int t) {
        int buf = t & 1;
        int p = t >> 4;
        int kc = (t & 15) * 32;
        const ushort* Ah = p ? d.A2h : d.A1h;
        const ushort* Al = p ? d.A2l : d.A1l;
        const ushort* Bh = p ? d.W2h : d.W1h;
        const ushort* Bl = p ? d.W2l : d.W1l;
        ushort* base = &lds[buf * 24576];
        #pragma unroll
        for (int it = 0; it < 4; ++it) {
            int db = (w * 4 + it) * 64;
            int dd = db + l;
            int q = dd >> 3, tp = dd & 7;
            int tl = tp ^ (q & 7);
            int r = (q << 1) | (tl >> 2);           // 0..255
            int s = tl & 3;
            size_t go = (size_t)r * HDIM + kc + s * 8;
            __builtin_amdgcn_global_load_lds(AS1(Ah + (size_t)m0 * HDIM + go),
                                             AS3(base + db * 8), 16, 0, 0);
            __builtin_amdgcn_global_load_lds(AS1(Al + (size_t)m0 * HDIM + go),
                                             AS3(base + 8192 + db * 8), 16, 0, 0);
        }
        #pragma unroll
        for (int it = 0; it < 2; ++it) {
            int db = (w * 2 + it) * 64;
            int dd = db + l;
            int q = dd >> 3, tp = dd & 7;
            int tl = tp ^ (q & 7);
            int r = (q << 1) | (tl >> 2);           // 0..127
            int s = tl & 3;
            size_t go = (size_t)r * HDIM + kc + s * 8;
            __builtin_amdgcn_global_load_lds(AS1(Bh + (size_t)n0 * HDIM + go),
                                             AS3(base + 16384 + db * 8), 16, 0, 0);
            __builtin_amdgcn_global_load_lds(AS1(Bl + (size_t)n0 * HDIM + go),
                                             AS3(base + 20480 + db * 8), 16, 0, 0);
        }
    };

    const int nch = d.np * 16;
    STAGE(0);

    for (int t = 0; t < nch; ++t) {
        __syncthreads();
        if (t + 1 < nch) STAGE(t + 1);
        ushort* base = &lds[(t & 1) * 24576];
        short8 bh[4], bl[4];
        #pragma unroll
        for (int g = 0; g < 4; ++g) {
            int row = wn * 64 + g * 16 + lrow;
            int off = swz(row, lk) * 8;
            bh[g] = *(const short8*)(base + 16384 + off);
            bl[g] = *(const short8*)(base + 20480 + off);
        }
        // A-streamed: per m-frag read ah/al then 12 MFMAs (hh, lh, hl order
        // per acc element — same accumulation order as the 128^2 kernel)
        #pragma unroll
        for (int fm = 0; fm < 8; ++fm) {
            int row = wm * 128 + fm * 16 + lrow;
            int off = swz(row, lk) * 8;
            short8 ah = *(const short8*)(base + off);
            short8 al = *(const short8*)(base + 8192 + off);
            #pragma unroll
            for (int g = 0; g < 4; ++g)
                acc[fm][g] = __builtin_amdgcn_mfma_f32_16x16x32_bf16(
                    ah, bh[g], acc[fm][g], 0, 0, 0);
            #pragma unroll
            for (int g = 0; g < 4; ++g)
                acc[fm][g] = __builtin_amdgcn_mfma_f32_16x16x32_bf16(
                    al, bh[g], acc[fm][g], 0, 0, 0);
            #pragma unroll
            for (int g = 0; g < 4; ++g)
                acc[fm][g] = __builtin_amdgcn_mfma_f32_16x16x32_bf16(
                    ah, bl[g], acc[fm][g], 0, 0, 0);
        }
    }

    #pragma unroll
    for (int fm = 0; fm < 8; ++fm)
        #pragma unroll
        for (int r = 0; r < 4; ++r) {
            int m = m0 + wm * 128 + fm * 16 + lk * 4 + r;
            size_t idx = (size_t)m * HDIM + u;
            float zi = acc[fm][0][r], zf = acc[fm][1][r];
            float zg = acc[fm][2][r], zo = acc[fm][3][r];
            float ig = 1.f / (1.f + __expf(-zi));
            float fg = 1.f / (1.f + __expf(-zf));
            float gg = 2.f / (1.f + __expf(-2.f * zg)) - 1.f;
            float og = 1.f / (1.f + __expf(-zo));
            float cn = fg * d.c[idx] + ig * gg;
            float hn = og * (2.f / (1.f + __expf(-2.f * cn)) - 1.f);
            d.c[idx] = cn;
            ushort hb = f2bf(hn);
            d.hh[idx] = hb;
            d.hl[idx] = f2bf(hn - bf2f(hb));
        }
}

// ---- output head: pred = (h_hi+h_lo) @ out_W^T + out_b, one wave per row ----
__global__ __launch_bounds__(256) void head_kernel(
    const ushort* __restrict__ hhi, const ushort* __restrict__ hlo,
    const float* __restrict__ Wout, const float* __restrict__ bout,
    float* __restrict__ out, float* __restrict__ xbuf, int t)
{
    int wave = (blockIdx.x * 256 + threadIdx.x) >> 6;
    int lane = threadIdx.x & 63;
    const ushort* hr = hhi + (size_t)wave * HDIM;
    const ushort* lr = hlo + (size_t)wave * HDIM;
    float s0 = 0.f, s1 = 0.f;
    #pragma unroll
    for (int k = lane; k < HDIM; k += 64) {
        float hv = bf2f(hr[k]) + bf2f(lr[k]);
        s0 += hv * Wout[k];
        s1 += hv * Wout[HDIM + k];
    }
    #pragma unroll
    for (int off = 32; off > 0; off >>= 1) {
        s0 += __shfl_down(s0, off);
        s1 += __shfl_down(s1, off);
    }
    if (lane == 0) {
        float p0 = s0 + bout[0], p1 = s1 + bout[1];
        out[(size_t)wave * (T_FUT * 2) + t * 2 + 0] = p0;
        out[(size_t)wave * (T_FUT * 2) + t * 2 + 1] = p1;
        xbuf[wave * 2 + 0] = p0;
        xbuf[wave * 2 + 1] = p1;
    }
}

extern "C" void kernel_launch(void* const* d_in, const int* in_sizes, int n_in,
                              void* d_out, int out_size, void* d_ws, size_t ws_size,
                              hipStream_t stream) {
    const float* history = (const float*)d_in[0];
    const float* eWih0 = (const float*)d_in[2];
    const float* eWhh0 = (const float*)d_in[3];
    const float* ebih0 = (const float*)d_in[4];
    const float* ebhh0 = (const float*)d_in[5];
    const float* eWih1 = (const float*)d_in[6];
    const float* eWhh1 = (const float*)d_in[7];
    const float* ebih1 = (const float*)d_in[8];
    const float* ebhh1 = (const float*)d_in[9];
    const float* dWih0 = (const float*)d_in[10];
    const float* dWhh0 = (const float*)d_in[11];
    const float* dbih0 = (const float*)d_in[12];
    const float* dbhh0 = (const float*)d_in[13];
    const float* dWih1 = (const float*)d_in[14];
    const float* dWhh1 = (const float*)d_in[15];
    const float* dbih1 = (const float*)d_in[16];
    const float* dbhh1 = (const float*)d_in[17];
    const float* outW  = (const float*)d_in[18];
    const float* outb  = (const float*)d_in[19];
    float* out = (float*)d_out;

    // ---- workspace layout ----
    const size_t M = (size_t)2048 * 512;
    ushort* whi = (ushort*)d_ws;
    ushort* wlo = whi + 6 * M;
    ushort* hb  = wlo + 6 * M;
    float*  c0  = (float*)(hb + 8 * M);
    float*  c1  = c0 + M;
    float*  xbuf = c1 + M;

    ushort* h0a_hi = hb + 0 * M; ushort* h0a_lo = hb + 1 * M;
    ushort* h0b_hi = hb + 2 * M; ushort* h0b_lo = hb + 3 * M;
    ushort* h1a_hi = hb + 4 * M; ushort* h1a_lo = hb + 5 * M;
    ushort* h1b_hi = hb + 6 * M; ushort* h1b_lo = hb + 7 * M;

    hipMemsetAsync(h0a_hi, 0, 2 * M * sizeof(ushort), stream);
    hipMemsetAsync(h1a_hi, 0, 2 * M * sizeof(ushort), stream);
    hipMemsetAsync(c0, 0, 2 * M * sizeof(float), stream);
    hipMemsetAsync(xbuf, 0, BDIM * 2 * sizeof(float), stream);

    SplitSrc ss;
    ss.src[0] = eWhh0; ss.src[1] = eWih1; ss.src[2] = eWhh1;
    ss.src[3] = dWhh0; ss.src[4] = dWih1; ss.src[5] = dWhh1;
    split_weights<<<dim3(2048, 6), 256, 0, stream>>>(ss, whi, wlo);

    #define WHI(j) (whi + (size_t)(j) * M)
    #define WLO(j) (wlo + (size_t)(j) * M)

    auto H0R_HI = [&](int s){ return (s & 1) ? h0b_hi : h0a_hi; };
    auto H0R_LO = [&](int s){ return (s & 1) ? h0b_lo : h0a_lo; };
    auto H0W_HI = [&](int s){ return (s & 1) ? h0a_hi : h0b_hi; };
    auto H0W_LO = [&](int s){ return (s & 1) ? h0a_lo : h0b_lo; };
    auto H1R_HI = [&](int s){ return (s & 1) ? h1b_hi : h1a_hi; };
    auto H1R_LO = [&](int s){ return (s & 1) ? h1b_lo : h1a_lo; };
    auto H1W_HI = [&](int s){ return (s & 1) ? h1a_hi : h1b_hi; };
    auto H1W_LO = [&](int s){ return (s & 1) ? h1a_lo : h1b_lo; };

    auto mkL0enc = [&](int s) {
        CellDesc d{};
        d.A1h = H0R_HI(s); d.A1l = H0R_LO(s); d.W1h = WHI(0); d.W1l = WLO(0);
        d.np = 1; d.x = history + s * 5; d.xs = T_HIST * 5; d.Kx = 5; d.Wx = eWih0;
        d.bih = ebih0; d.bhh = ebhh0; d.c = c0; d.hh = H0W_HI(s); d.hl = H0W_LO(s);
        return d;
    };
    auto mkL1enc = [&](int s) {
        CellDesc d{};
        d.A1h = H0W_HI(s); d.A1l = H0W_LO(s); d.W1h = WHI(1); d.W1l = WLO(1);
        d.A2h = H1R_HI(s); d.A2l = H1R_LO(s); d.W2h = WHI(2); d.W2l = WLO(2);
        d.np = 2; d.Kx = 0; d.xs = 0;
        d.bih = ebih1; d.bhh = ebhh1; d.c = c1; d.hh = H1W_HI(s); d.hl = H1W_LO(s);
        return d;
    };
    auto mkD0 = [&](int s) {
        CellDesc d{};
        d.A1h = H0R_HI(s); d.A1l = H0R_LO(s); d.W1h = WHI(3); d.W1l = WLO(3);
        d.np = 1; d.x = xbuf; d.xs = 2; d.Kx = 2; d.Wx = dWih0;
        d.bih = dbih0; d.bhh = dbhh0; d.c = c0; d.hh = H0W_HI(s); d.hl = H0W_LO(s);
        return d;
    };
    auto mkD1 = [&](int s) {
        CellDesc d{};
        d.A1h = H0W_HI(s); d.A1l = H0W_LO(s); d.W1h = WHI(4); d.W1l = WLO(4);
        d.A2h = H1R_HI(s); d.A2l = H1R_LO(s); d.W2h = WHI(5); d.W2l = WLO(5);
        d.np = 2; d.Kx = 0; d.xs = 0;
        d.bih = dbih1; d.bhh = dbhh1; d.c = c1; d.hh = H1W_HI(s); d.hl = H1W_LO(s);
        return d;
    };

    dim3 blk(256);

    // encoder step 0, layer 0 alone (128^2 kernel, full grid)
    {
        CellDesc d = mkL0enc(0);
        lstm_cells<<<256, blk, 0, stream>>>(d, d);
    }
    // paired encoder on the 256x128 kernel: [L1(s) || L0(s+1)];
    // last pair feeds the decoder (D0(50), x = zeroed xbuf)
    for (int s = 0; s < T_HIST; ++s) {
        CellDesc dL1 = mkL1enc(s);
        CellDesc dNx = (s + 1 < T_HIST) ? mkL0enc(s + 1) : mkD0(T_HIST);
        lstm_cells_big<<<256, blk, 0, stream>>>(dL1, dNx);
    }
    // decoder: D1(s) -> head(s) -> D0(s+1)  (128^2 kernel, unchanged)
    for (int s = T_HIST; s < T_HIST + T_FUT; ++s) {
        CellDesc d1 = mkD1(s);
        lstm_cells<<<256, blk, 0, stream>>>(d1, d1);
        head_kernel<<<512, blk, 0, stream>>>(H1W_HI(s), H1W_LO(s), outW, outb,
                                             out, xbuf, s - T_HIST);
        if (s + 1 < T_HIST + T_FUT) {
            CellDesc d0 = mkD0(s + 1);
            lstm_cells<<<256, blk, 0, stream>>>(d0, d0);
        }
    }
    #undef WHI
    #undef WLO
}